// Round 5
// baseline (1256.007 us; speedup 1.0000x reference)
//
#include <hip/hip_runtime.h>
#include <hip/hip_bf16.h>

// ResAttention fused forward: out = (v [B,L,H,D] , attn_map [B,H,L,S]), fp32.
// B=4, L=S=2048, H=16, E=D=64.
// Fast path (needs ws >= 50331648 B):
//   conv_all: Q (pre-scaled by 1/8*log2e), K -> bf16 [b,h,l,e]; V -> bf16 [b,h,d,s]
//   attn_main: per (b,h,128 q-rows) block, 4 waves (one 32-q block each),
//   32x32x16 MFMA. Swapped QK^T (A=K s-rows, B=Q q-cols) => lane's entire P
//   lives on one q-row (q = lane&31). Phase 1: row sums via 4-slot K ring,
//   2-chunk iterations, counted vmcnt. Phase 2: recompute scores, write
//   normalized P (8 float4 nt stores/chunk) + PV; K/V dbuf, vmcnt(8).

typedef __attribute__((ext_vector_type(4)))  float  f32x4;
typedef __attribute__((ext_vector_type(16))) float  f32x16;
typedef __attribute__((ext_vector_type(8)))  short  short8;
typedef __attribute__((ext_vector_type(4)))  short  short4v;
typedef __attribute__((ext_vector_type(4)))  unsigned short u16x4;

#define Z16 {0.f,0.f,0.f,0.f,0.f,0.f,0.f,0.f,0.f,0.f,0.f,0.f,0.f,0.f,0.f,0.f}

__device__ __forceinline__ unsigned short bf(float x) {
  return __builtin_bit_cast(unsigned short, __float2bfloat16(x));
}

__device__ __forceinline__ unsigned short f2bf(float f) {
  unsigned int u = __builtin_bit_cast(unsigned int, f);
  return (unsigned short)((u + 0x7FFFu + ((u >> 16) & 1u)) >> 16);  // RNE
}

#define MFMA16(A, Bv, C) __builtin_amdgcn_mfma_f32_16x16x32_bf16(A, Bv, C, 0, 0, 0)
#define MFMA32(A, Bv, C) __builtin_amdgcn_mfma_f32_32x32x16_bf16(A, Bv, C, 0, 0, 0)

// ============================ prologue kernel ============================

__global__ __launch_bounds__(256) void conv_all(const float* __restrict__ Q,
                                                const float* __restrict__ K,
                                                const float* __restrict__ V,
                                                unsigned short* __restrict__ Qbf,
                                                unsigned short* __restrict__ Kbf,
                                                unsigned short* __restrict__ VTbf) {
  __shared__ unsigned short T[64][68];
  if (blockIdx.x < 8192) {
    int idx = blockIdx.x * 256 + threadIdx.x;   // 2^21 total
    int isK = idx >> 20;
    int rem = idx & 0xFFFFF;
    int e0 = (rem & 7) << 3;
    int h  = (rem >> 3) & 15;
    int l  = (rem >> 7) & 2047;
    int b  = rem >> 18;
    const float* src = (isK ? K : Q) + (((size_t)(b * 2048 + l)) * 16 + h) * 64 + e0;
    unsigned short* dst = (isK ? Kbf : Qbf) + (((size_t)(b * 16 + h)) * 2048 + l) * 64 + e0;
    float sc = isK ? 1.0f : 0.18033688011112042f;  // (1/sqrt(64))*log2(e)
    float4 a = *(const float4*)src;
    float4 c = *(const float4*)(src + 4);
    u16x4 o0 = { bf(a.x * sc), bf(a.y * sc), bf(a.z * sc), bf(a.w * sc) };
    u16x4 o1 = { bf(c.x * sc), bf(c.y * sc), bf(c.z * sc), bf(c.w * sc) };
    *(u16x4*)dst = o0;
    *(u16x4*)(dst + 4) = o1;
  } else {
    int bid = blockIdx.x - 8192;     // (b*16+h)*32 + sc
    int sc = bid & 31, bh = bid >> 5;
    int h = bh & 15, b = bh >> 4;
    int t = threadIdx.x;
    int srow = t >> 2, d0 = (t & 3) << 4;
    const float* src = V + (((size_t)(b * 2048 + sc * 64 + srow)) * 16 + h) * 64 + d0;
    float4 v0 = *(const float4*)(src + 0);
    float4 v1 = *(const float4*)(src + 4);
    float4 v2 = *(const float4*)(src + 8);
    float4 v3 = *(const float4*)(src + 12);
    T[d0+ 0][srow]=bf(v0.x); T[d0+ 1][srow]=bf(v0.y); T[d0+ 2][srow]=bf(v0.z); T[d0+ 3][srow]=bf(v0.w);
    T[d0+ 4][srow]=bf(v1.x); T[d0+ 5][srow]=bf(v1.y); T[d0+ 6][srow]=bf(v1.z); T[d0+ 7][srow]=bf(v1.w);
    T[d0+ 8][srow]=bf(v2.x); T[d0+ 9][srow]=bf(v2.y); T[d0+10][srow]=bf(v2.z); T[d0+11][srow]=bf(v2.w);
    T[d0+12][srow]=bf(v3.x); T[d0+13][srow]=bf(v3.y); T[d0+14][srow]=bf(v3.z); T[d0+15][srow]=bf(v3.w);
    __syncthreads();
    int d = t >> 2, s0 = (t & 3) << 4;
    unsigned short* dst = VTbf + ((size_t)bh * 64 + d) * 2048 + sc * 64 + s0;
#pragma unroll
    for (int j = 0; j < 16; j += 4) {
      u16x4 x = { T[d][s0 + j], T[d][s0 + j + 1], T[d][s0 + j + 2], T[d][s0 + j + 3] };
      *(u16x4*)(dst + j) = x;
    }
  }
}

// ============================ main kernel ============================

__device__ __forceinline__ void gll16(const void* g, void* l) {
  __builtin_amdgcn_global_load_lds(
      (const __attribute__((address_space(1))) unsigned int*)g,
      (__attribute__((address_space(3))) unsigned int*)l, 16, 0, 0);
}

// Stage 16 rows (this wave's quarter) of a 64x64 bf16 tile into LDS,
// XOR-swizzled via pre-swizzled per-lane global source (linear LDS dest).
__device__ __forceinline__ void stage16(const unsigned short* gsrc, int rowStride,
                                        unsigned short* dstRow0, int lane) {
  int rr = lane >> 3;                     // row within 8-row group (= row&7)
  int cc = ((lane & 7) ^ rr) << 3;        // swizzled source column (elements)
  gll16(gsrc + (size_t)rr * rowStride + cc,       dstRow0);
  gll16(gsrc + (size_t)(8 + rr) * rowStride + cc, dstRow0 + 8 * 64);
}

// Swizzled b128 fragment read: data column colb (bytes) of tile row `row`.
__device__ __forceinline__ short8 frag(const unsigned short* tile, int row, int colb) {
  return *(const short8*)((const char*)tile + row * 128 + (colb ^ ((row & 7) << 4)));
}

// exp2 + normalize one 32-score half-chunk; store fp32 attn + bf16 P to LDS.
__device__ __forceinline__ void emit_p(const f32x16 st, float rinv, float* aBase,
                                       unsigned short* prowBase, int hi) {
#pragma unroll
  for (int rr = 0; rr < 4; ++rr) {
    f32x4 p;
#pragma unroll
    for (int i = 0; i < 4; ++i)
      p[i] = __builtin_amdgcn_exp2f(st[rr * 4 + i]) * rinv;
    __builtin_nontemporal_store(p, (f32x4*)(aBase + rr * 8 + 4 * hi));
    u16x4 pb = { bf(p[0]), bf(p[1]), bf(p[2]), bf(p[3]) };
    *(u16x4*)(prowBase + rr * 8 + hi * 4) = pb;
  }
}

__global__ __launch_bounds__(256, 3) void attn_main(
    const unsigned short* __restrict__ Qbf, const unsigned short* __restrict__ Kbf,
    const unsigned short* __restrict__ VTbf, float* __restrict__ Og,
    float* __restrict__ Ag) {

  // bijective XCD swizzle: 1024 = 8 * 128
  int wg = ((blockIdx.x & 7) << 7) | (blockIdx.x >> 3);
  int qt = wg & 15, bh = wg >> 4;      // 16 q-tiles of 128 rows
  int h = bh & 15, b = bh >> 4;

  int tid = threadIdx.x, lane = tid & 63, w = tid >> 6;
  int cl = lane & 31, hi = lane >> 5;
  int q0 = qt * 128;

  __shared__ __align__(16) unsigned short Kb[2][64][64];   // 16 KB
  __shared__ __align__(16) unsigned short Vb[2][64][64];   // 16 KB
  __shared__ __align__(16) unsigned short Pw[4][32][72];   // 18 KB, per-wave P

  const unsigned short* kg = Kbf + (size_t)bh * 2048 * 64 + (size_t)(w * 16) * 64;
  const unsigned short* vg = VTbf + (size_t)bh * 64 * 2048 + (size_t)(w * 16) * 2048;

  // Q fragments: B-operand, col=q=cl, k = kc*16 + hi*8 + j. Registers for life.
  const unsigned short* qrow = Qbf + ((size_t)bh * 2048 + q0 + w * 32 + cl) * 64;
  short8 qf[4];
#pragma unroll
  for (int kc = 0; kc < 4; ++kc)
    qf[kc] = *(const short8*)(qrow + kc * 16 + hi * 8);

  // ---------------- phase 1: row sums, 4-slot ring, 2 chunks/iter ----------------
  stage16(kg,            64, &Kb[0][w * 16][0], lane);
  stage16(kg + 4096,     64, &Kb[1][w * 16][0], lane);
  stage16(kg + 2 * 4096, 64, &Vb[0][w * 16][0], lane);
  stage16(kg + 3 * 4096, 64, &Vb[1][w * 16][0], lane);

  float lsum = 0.0f;
  for (int ii = 0; ii < 16; ++ii) {
    if (ii < 15) {
      asm volatile("s_waitcnt vmcnt(4)" ::: "memory");   // this iter's pair ready
    } else {
      asm volatile("s_waitcnt vmcnt(0)" ::: "memory");
    }
    __builtin_amdgcn_s_barrier();

    const int hsel = ii & 1;
    const unsigned short* tA = hsel ? &Vb[0][0][0] : &Kb[0][0][0];
    const unsigned short* tB = hsel ? &Vb[1][0][0] : &Kb[1][0][0];

#pragma unroll
    for (int tt = 0; tt < 2; ++tt) {
      const unsigned short* kt = tt ? tB : tA;
      f32x16 sa = Z16, sb = Z16;
      __builtin_amdgcn_s_setprio(1);
#pragma unroll
      for (int kc = 0; kc < 4; ++kc) {
        short8 ka = frag(kt, cl,      kc * 32 + hi * 16);   // s-rows 0..31
        short8 kb = frag(kt, 32 + cl, kc * 32 + hi * 16);   // s-rows 32..63
        sa = MFMA32(ka, qf[kc], sa);
        sb = MFMA32(kb, qf[kc], sb);
      }
      __builtin_amdgcn_s_setprio(0);
      float a0 = 0.f, a1 = 0.f, a2 = 0.f, a3 = 0.f;
#pragma unroll
      for (int r = 0; r < 4; ++r) {
        a0 += __builtin_amdgcn_exp2f(sa[r]);
        a1 += __builtin_amdgcn_exp2f(sa[4 + r]);
        a2 += __builtin_amdgcn_exp2f(sa[8 + r]);
        a3 += __builtin_amdgcn_exp2f(sa[12 + r]);
        a0 += __builtin_amdgcn_exp2f(sb[r]);
        a1 += __builtin_amdgcn_exp2f(sb[4 + r]);
        a2 += __builtin_amdgcn_exp2f(sb[8 + r]);
        a3 += __builtin_amdgcn_exp2f(sb[12 + r]);
      }
      lsum += (a0 + a1) + (a2 + a3);
    }

    __builtin_amdgcn_s_barrier();    // all waves done reading this pair's slots

    if (ii < 14) {
      const unsigned short* nk = kg + (size_t)(2 * ii + 4) * 4096;
      unsigned short* dA = hsel ? &Vb[0][w * 16][0] : &Kb[0][w * 16][0];
      unsigned short* dB = hsel ? &Vb[1][w * 16][0] : &Kb[1][w * 16][0];
      stage16(nk,        64, dA, lane);
      stage16(nk + 4096, 64, dB, lane);
    }
  }
  lsum += __shfl_xor(lsum, 32, 64);      // sum over hi halves; q = cl per lane
  float rinv = 1.0f / lsum;

  // ---------------- phase 2: P write + PV ----------------
  f32x16 oacc0 = Z16, oacc1 = Z16;

  stage16(kg, 64, &Kb[0][w * 16][0], lane);
  stage16(vg, 2048, &Vb[0][w * 16][0], lane);
  asm volatile("s_waitcnt vmcnt(0)" ::: "memory");
  __builtin_amdgcn_s_barrier();

  float* aQ = Ag + ((size_t)bh * 2048 + (size_t)(q0 + w * 32 + cl)) * 2048;
  unsigned short* prow = &Pw[w][cl][0];

  for (int ch = 0; ch < 32; ++ch) {
    int cur = ch & 1;
    if (ch < 31) {
      stage16(kg + (size_t)(ch + 1) * 4096, 64, &Kb[cur ^ 1][w * 16][0], lane);
      stage16(vg + (size_t)(ch + 1) * 64, 2048, &Vb[cur ^ 1][w * 16][0], lane);
    }
    const unsigned short* kt = &Kb[cur][0][0];
    const unsigned short* vt = &Vb[cur][0][0];

    // QK^T: D[s][q], q = cl, s = sblk*32 + (reg&3)+8*(reg>>2)+4*hi
    f32x16 sa = Z16, sb = Z16;
    __builtin_amdgcn_s_setprio(1);
#pragma unroll
    for (int kc = 0; kc < 4; ++kc) {
      short8 ka = frag(kt, cl,      kc * 32 + hi * 16);
      short8 kb = frag(kt, 32 + cl, kc * 32 + hi * 16);
      sa = MFMA32(ka, qf[kc], sa);
      sb = MFMA32(kb, qf[kc], sb);
    }
    __builtin_amdgcn_s_setprio(0);

    // normalized P: fp32 attn_map (nt float4) + bf16 to per-wave LDS row
    emit_p(sa, rinv, aQ + ch * 64,      prow,      hi);
    emit_p(sb, rinv, aQ + ch * 64 + 32, prow + 32, hi);

    // PV: A=P[q=cl][k=s], B=V^T[d rows][s cols]; D col = d, rows = q
    __builtin_amdgcn_s_setprio(1);
#pragma unroll
    for (int kc = 0; kc < 4; ++kc) {
      short8 pa = *(const short8*)(prow + kc * 16 + hi * 8);
      short8 v0 = frag(vt, cl,      kc * 32 + hi * 16);
      short8 v1 = frag(vt, 32 + cl, kc * 32 + hi * 16);
      oacc0 = MFMA32(pa, v0, oacc0);
      oacc1 = MFMA32(pa, v1, oacc1);
    }
    __builtin_amdgcn_s_setprio(0);

    // wait the 4 gll (oldest after residual stores); leave 8 nt stores in flight
    asm volatile("s_waitcnt vmcnt(8)" ::: "memory");
    __builtin_amdgcn_s_barrier();
  }

  // v out: [b, l, h, d]; lane holds q-rows (r&3)+8*(r>>2)+4*hi, d = db*32+cl
#pragma unroll
  for (int r = 0; r < 16; ++r) {
    int q = q0 + w * 32 + (r & 3) + 8 * (r >> 2) + 4 * hi;
    size_t base = (((size_t)b * 2048 + q) * 16 + h) * 64 + cl;
    Og[base]      = oacc0[r];
    Og[base + 32] = oacc1[r];
  }
}

// ============================ fp32 fallback ============================

__global__ __launch_bounds__(256, 2) void attn_fused(
    const float* __restrict__ Qg, const float* __restrict__ Kg,
    const float* __restrict__ Vg, float* __restrict__ Og,
    float* __restrict__ Ag) {

  const int qt = blockIdx.x & 31;
  const int bh = blockIdx.x >> 5;
  const int h  = bh & 15;
  const int b  = bh >> 4;

  const int tid  = threadIdx.x;
  const int lane = tid & 63;
  const int w    = tid >> 6;
  const int g    = lane >> 4;
  const int r16  = lane & 15;

  __shared__ __align__(16) unsigned short Qbuf[64][72];
  __shared__ __align__(16) unsigned short Kbuf[64][72];
  __shared__ __align__(16) unsigned short VT[64][68];
  __shared__ __align__(16) unsigned short Pbuf[4][16][72];

  const size_t inbase = (size_t)b * (2048u * 1024u) + (size_t)h * 64u;
  const int q0 = qt << 6;

  const int srow = tid >> 2;
  const int sd0  = (tid & 3) << 4;

  {
    const float sc = 0.18033688011112042f;
    const float* gp = Qg + inbase + (size_t)(q0 + srow) * 1024u + sd0;
    float4 va = *(const float4*)(gp + 0);
    float4 vb = *(const float4*)(gp + 4);
    float4 vc = *(const float4*)(gp + 8);
    float4 vd = *(const float4*)(gp + 12);
    unsigned short* dst = &Qbuf[srow][sd0];
    dst[0]=f2bf(va.x*sc); dst[1]=f2bf(va.y*sc); dst[2]=f2bf(va.z*sc); dst[3]=f2bf(va.w*sc);
    dst[4]=f2bf(vb.x*sc); dst[5]=f2bf(vb.y*sc); dst[6]=f2bf(vb.z*sc); dst[7]=f2bf(vb.w*sc);
    dst[8]=f2bf(vc.x*sc); dst[9]=f2bf(vc.y*sc); dst[10]=f2bf(vc.z*sc); dst[11]=f2bf(vc.w*sc);
    dst[12]=f2bf(vd.x*sc); dst[13]=f2bf(vd.y*sc); dst[14]=f2bf(vd.z*sc); dst[15]=f2bf(vd.w*sc);
  }
  __syncthreads();

  const short8 qf0 = *(const short8*)&Qbuf[w*16 + r16][g*8];
  const short8 qf1 = *(const short8*)&Qbuf[w*16 + r16][32 + g*8];

  f32x4 mrow = { -3e38f, -3e38f, -3e38f, -3e38f };
  f32x4 lrow = { 0.f, 0.f, 0.f, 0.f };

  for (int ch = 0; ch < 32; ++ch) {
    __syncthreads();
    {
      const float* gp = Kg + inbase + (size_t)(ch*64 + srow) * 1024u + sd0;
      float4 va = *(const float4*)(gp + 0);
      float4 vb = *(const float4*)(gp + 4);
      float4 vc = *(const float4*)(gp + 8);
      float4 vd = *(const float4*)(gp + 12);
      unsigned short* dst = &Kbuf[srow][sd0];
      dst[0]=f2bf(va.x); dst[1]=f2bf(va.y); dst[2]=f2bf(va.z); dst[3]=f2bf(va.w);
      dst[4]=f2bf(vb.x); dst[5]=f2bf(vb.y); dst[6]=f2bf(vb.z); dst[7]=f2bf(vb.w);
      dst[8]=f2bf(vc.x); dst[9]=f2bf(vc.y); dst[10]=f2bf(vc.z); dst[11]=f2bf(vc.w);
      dst[12]=f2bf(vd.x); dst[13]=f2bf(vd.y); dst[14]=f2bf(vd.z); dst[15]=f2bf(vd.w);
    }
    __syncthreads();

    f32x4 st[4];
#pragma unroll
    for (int t = 0; t < 4; ++t) {
      const short8 kf0 = *(const short8*)&Kbuf[t*16 + r16][g*8];
      const short8 kf1 = *(const short8*)&Kbuf[t*16 + r16][32 + g*8];
      f32x4 z = {0.f, 0.f, 0.f, 0.f};
      z = MFMA16(qf0, kf0, z);
      z = MFMA16(qf1, kf1, z);
      st[t] = z;
    }

    f32x4 cm = st[0];
#pragma unroll
    for (int t = 1; t < 4; ++t)
#pragma unroll
      for (int r = 0; r < 4; ++r) cm[r] = fmaxf(cm[r], st[t][r]);
#pragma unroll
    for (int i = 1; i < 16; i <<= 1)
#pragma unroll
      for (int r = 0; r < 4; ++r) cm[r] = fmaxf(cm[r], __shfl_xor(cm[r], i, 64));

    f32x4 mn, corr, sum = {0.f, 0.f, 0.f, 0.f};
#pragma unroll
    for (int r = 0; r < 4; ++r) {
      mn[r]   = fmaxf(mrow[r], cm[r]);
      corr[r] = exp2f(mrow[r] - mn[r]);
    }
#pragma unroll
    for (int t = 0; t < 4; ++t)
#pragma unroll
      for (int r = 0; r < 4; ++r) sum[r] += exp2f(st[t][r] - mn[r]);
#pragma unroll
    for (int i = 1; i < 16; i <<= 1)
#pragma unroll
      for (int r = 0; r < 4; ++r) sum[r] += __shfl_xor(sum[r], i, 64);
#pragma unroll
    for (int r = 0; r < 4; ++r) {
      lrow[r] = lrow[r] * corr[r] + sum[r];
      mrow[r] = mn[r];
    }
  }

  f32x4 rinv;
#pragma unroll
  for (int r = 0; r < 4; ++r) rinv[r] = 1.0f / lrow[r];

  f32x4 oacc[4];
#pragma unroll
  for (int t = 0; t < 4; ++t) oacc[t] = (f32x4){0.f, 0.f, 0.f, 0.f};

  float* aRow = Ag + ((size_t)bh * 2048u + (size_t)(q0 + w*16 + 4*g)) * 2048u;

  for (int ch = 0; ch < 32; ++ch) {
    __syncthreads();
    {
      const float* gp = Kg + inbase + (size_t)(ch*64 + srow) * 1024u + sd0;
      float4 va = *(const float4*)(gp + 0);
      float4 vb = *(const float4*)(gp + 4);
      float4 vc = *(const float4*)(gp + 8);
      float4 vd = *(const float4*)(gp + 12);
      unsigned short* dst = &Kbuf[srow][sd0];
      dst[0]=f2bf(va.x); dst[1]=f2bf(va.y); dst[2]=f2bf(va.z); dst[3]=f2bf(va.w);
      dst[4]=f2bf(vb.x); dst[5]=f2bf(vb.y); dst[6]=f2bf(vb.z); dst[7]=f2bf(vb.w);
      dst[8]=f2bf(vc.x); dst[9]=f2bf(vc.y); dst[10]=f2bf(vc.z); dst[11]=f2bf(vc.w);
      dst[12]=f2bf(vd.x); dst[13]=f2bf(vd.y); dst[14]=f2bf(vd.z); dst[15]=f2bf(vd.w);
    }
    {
      const float* gp = Vg + inbase + (size_t)(ch*64 + lane) * 1024u + (size_t)(w*16);
      float4 va = *(const float4*)(gp + 0);
      float4 vb = *(const float4*)(gp + 4);
      float4 vc = *(const float4*)(gp + 8);
      float4 vd = *(const float4*)(gp + 12);
      const int dbase = w * 16;
      VT[dbase+ 0][lane]=f2bf(va.x); VT[dbase+ 1][lane]=f2bf(va.y);
      VT[dbase+ 2][lane]=f2bf(va.z); VT[dbase+ 3][lane]=f2bf(va.w);
      VT[dbase+ 4][lane]=f2bf(vb.x); VT[dbase+ 5][lane]=f2bf(vb.y);
      VT[dbase+ 6][lane]=f2bf(vb.z); VT[dbase+ 7][lane]=f2bf(vb.w);
      VT[dbase+ 8][lane]=f2bf(vc.x); VT[dbase+ 9][lane]=f2bf(vc.y);
      VT[dbase+10][lane]=f2bf(vc.z); VT[dbase+11][lane]=f2bf(vc.w);
      VT[dbase+12][lane]=f2bf(vd.x); VT[dbase+13][lane]=f2bf(vd.y);
      VT[dbase+14][lane]=f2bf(vd.z); VT[dbase+15][lane]=f2bf(vd.w);
    }
    __syncthreads();

    f32x4 st[4];
#pragma unroll
    for (int t = 0; t < 4; ++t) {
      const short8 kf0 = *(const short8*)&Kbuf[t*16 + r16][g*8];
      const short8 kf1 = *(const short8*)&Kbuf[t*16 + r16][32 + g*8];
      f32x4 z = {0.f, 0.f, 0.f, 0.f};
      z = MFMA16(qf0, kf0, z);
      z = MFMA16(qf1, kf1, z);
      st[t] = z;
    }

#pragma unroll
    for (int t = 0; t < 4; ++t) {
#pragma unroll
      for (int r = 0; r < 4; ++r) {
        float p = exp2f(st[t][r] - mrow[r]) * rinv[r];
        aRow[(size_t)r * 2048u + (size_t)(ch*64 + t*16 + r16)] = p;
        Pbuf[w][4*g + r][t*16 + r16] = f2bf(p);
      }
    }

#pragma unroll
    for (int c = 0; c < 2; ++c) {
      const short8 pa = *(const short8*)&Pbuf[w][r16][c*32 + g*8];
#pragma unroll
      for (int t = 0; t < 4; ++t) {
        const unsigned short* vp = &VT[t*16 + r16][c*32 + g*8];
        short4v lo = *(const short4v*)vp;
        short4v hi = *(const short4v*)(vp + 4);
        short8 vbf = { lo[0], lo[1], lo[2], lo[3], hi[0], hi[1], hi[2], hi[3] };
        oacc[t] = MFMA16(pa, vbf, oacc[t]);
      }
    }
  }

  float* op = Og + (((size_t)b * 2048u + (size_t)(q0 + w*16 + 4*g)) * 16u + (size_t)h) * 64u;
#pragma unroll
  for (int t = 0; t < 4; ++t)
#pragma unroll
    for (int r = 0; r < 4; ++r)
      op[(size_t)r * 1024u + (size_t)(t*16 + r16)] = oacc[t][r];
}

// ============================ launcher ============================

extern "C" void kernel_launch(void* const* d_in, const int* in_sizes, int n_in,
                              void* d_out, int out_size, void* d_ws, size_t ws_size,
                              hipStream_t stream) {
  const float* Q = (const float*)d_in[0];
  const float* K = (const float*)d_in[1];
  const float* V = (const float*)d_in[2];
  float* Og = (float*)d_out;               // v: 4*2048*16*64 = 8388608
  float* Ag = (float*)d_out + 8388608;     // attn_map: 4*16*2048*2048

  const size_t NEED = 3ull * 8388608ull * 2ull;  // Qbf + Kbf + VTbf = 50331648 B
  if (ws_size >= NEED) {
    unsigned short* Qbf  = (unsigned short*)d_ws;
    unsigned short* Kbf  = Qbf + 8388608;
    unsigned short* VTbf = Kbf + 8388608;
    conv_all<<<dim3(10240), dim3(256), 0, stream>>>(Q, K, V, Qbf, Kbf, VTbf);
    attn_main<<<dim3(1024), dim3(256), 0, stream>>>(Qbf, Kbf, VTbf, Og, Ag);
  } else {
    attn_fused<<<dim3(2048), dim3(256), 0, stream>>>(Q, K, V, Og, Ag);
  }
}

// Round 6
// 246.195 us; speedup vs baseline: 5.1017x; 5.1017x over previous
//
#include <hip/hip_runtime.h>
#include <hip/hip_bf16.h>

// ResAttention fused forward: out = (v [B,L,H,D] , attn_map [B,H,L,S]), fp32.
// B=4, L=S=2048, H=16, E=D=64.
// Fast path (needs ws >= 50331648 B):
//   conv_all: Q (pre-scaled by 1/8*log2e), K -> bf16 [b,h,l,e]; V -> bf16 [b,h,d,s]
//   attn_main (R4 structure): per (b,h,64 q-rows) block, 4 waves.
//     phase 1: row sums of exp2(scores), 4-slot K ring, 2 chunks/iter, counted vmcnt.
//     phase 2: recompute scores, P -> bf16 in per-wave LDS; attn_map written by
//              re-reading P in store-order => each store inst covers 4 rows x 256B
//              contiguous (R5 counters showed scattered/partial-line stores were
//              the bottleneck: WRITE_SIZE 1.87GB vs 1.07GB logical).

typedef __attribute__((ext_vector_type(4)))  float  f32x4;
typedef __attribute__((ext_vector_type(8)))  short  short8;
typedef __attribute__((ext_vector_type(4)))  short  short4v;
typedef __attribute__((ext_vector_type(4)))  unsigned short u16x4;

__device__ __forceinline__ unsigned short bf(float x) {
  return __builtin_bit_cast(unsigned short, __float2bfloat16(x));
}

__device__ __forceinline__ float bf2f(unsigned short u) {
  return __builtin_bit_cast(float, (unsigned int)u << 16);
}

__device__ __forceinline__ unsigned short f2bf(float f) {
  unsigned int u = __builtin_bit_cast(unsigned int, f);
  return (unsigned short)((u + 0x7FFFu + ((u >> 16) & 1u)) >> 16);  // RNE
}

#define MFMA16(A, Bv, C) __builtin_amdgcn_mfma_f32_16x16x32_bf16(A, Bv, C, 0, 0, 0)

// ============================ prologue kernel ============================

__global__ __launch_bounds__(256) void conv_all(const float* __restrict__ Q,
                                                const float* __restrict__ K,
                                                const float* __restrict__ V,
                                                unsigned short* __restrict__ Qbf,
                                                unsigned short* __restrict__ Kbf,
                                                unsigned short* __restrict__ VTbf) {
  __shared__ unsigned short T[64][68];
  if (blockIdx.x < 8192) {
    int idx = blockIdx.x * 256 + threadIdx.x;   // 2^21 total
    int isK = idx >> 20;
    int rem = idx & 0xFFFFF;
    int e0 = (rem & 7) << 3;
    int h  = (rem >> 3) & 15;
    int l  = (rem >> 7) & 2047;
    int b  = rem >> 18;
    const float* src = (isK ? K : Q) + (((size_t)(b * 2048 + l)) * 16 + h) * 64 + e0;
    unsigned short* dst = (isK ? Kbf : Qbf) + (((size_t)(b * 16 + h)) * 2048 + l) * 64 + e0;
    float sc = isK ? 1.0f : 0.18033688011112042f;  // (1/sqrt(64))*log2(e)
    float4 a = *(const float4*)src;
    float4 c = *(const float4*)(src + 4);
    u16x4 o0 = { bf(a.x * sc), bf(a.y * sc), bf(a.z * sc), bf(a.w * sc) };
    u16x4 o1 = { bf(c.x * sc), bf(c.y * sc), bf(c.z * sc), bf(c.w * sc) };
    *(u16x4*)dst = o0;
    *(u16x4*)(dst + 4) = o1;
  } else {
    int bid = blockIdx.x - 8192;     // (b*16+h)*32 + sc
    int sc = bid & 31, bh = bid >> 5;
    int h = bh & 15, b = bh >> 4;
    int t = threadIdx.x;
    int srow = t >> 2, d0 = (t & 3) << 4;
    const float* src = V + (((size_t)(b * 2048 + sc * 64 + srow)) * 16 + h) * 64 + d0;
    float4 v0 = *(const float4*)(src + 0);
    float4 v1 = *(const float4*)(src + 4);
    float4 v2 = *(const float4*)(src + 8);
    float4 v3 = *(const float4*)(src + 12);
    T[d0+ 0][srow]=bf(v0.x); T[d0+ 1][srow]=bf(v0.y); T[d0+ 2][srow]=bf(v0.z); T[d0+ 3][srow]=bf(v0.w);
    T[d0+ 4][srow]=bf(v1.x); T[d0+ 5][srow]=bf(v1.y); T[d0+ 6][srow]=bf(v1.z); T[d0+ 7][srow]=bf(v1.w);
    T[d0+ 8][srow]=bf(v2.x); T[d0+ 9][srow]=bf(v2.y); T[d0+10][srow]=bf(v2.z); T[d0+11][srow]=bf(v2.w);
    T[d0+12][srow]=bf(v3.x); T[d0+13][srow]=bf(v3.y); T[d0+14][srow]=bf(v3.z); T[d0+15][srow]=bf(v3.w);
    __syncthreads();
    int d = t >> 2, s0 = (t & 3) << 4;
    unsigned short* dst = VTbf + ((size_t)bh * 64 + d) * 2048 + sc * 64 + s0;
#pragma unroll
    for (int j = 0; j < 16; j += 4) {
      u16x4 x = { T[d][s0 + j], T[d][s0 + j + 1], T[d][s0 + j + 2], T[d][s0 + j + 3] };
      *(u16x4*)(dst + j) = x;
    }
  }
}

// ============================ main kernel ============================

__device__ __forceinline__ void gll16(const void* g, void* l) {
  __builtin_amdgcn_global_load_lds(
      (const __attribute__((address_space(1))) unsigned int*)g,
      (__attribute__((address_space(3))) unsigned int*)l, 16, 0, 0);
}

// Stage 16 rows (this wave's quarter) of a 64x64 bf16 tile into LDS,
// XOR-swizzled via pre-swizzled per-lane global source (linear LDS dest).
__device__ __forceinline__ void stage16(const unsigned short* gsrc, int rowStride,
                                        unsigned short* dstRow0, int lane) {
  int rr = lane >> 3;                     // row within 8-row group (= row&7)
  int cc = ((lane & 7) ^ rr) << 3;        // swizzled source column (elements)
  gll16(gsrc + (size_t)rr * rowStride + cc,       dstRow0);
  gll16(gsrc + (size_t)(8 + rr) * rowStride + cc, dstRow0 + 8 * 64);
}

// Swizzled b128 fragment read: data column colb (bytes) of tile row `row`.
__device__ __forceinline__ short8 frag(const unsigned short* tile, int row, int colb) {
  return *(const short8*)((const char*)tile + row * 128 + (colb ^ ((row & 7) << 4)));
}

__global__ __launch_bounds__(256, 3) void attn_main(
    const unsigned short* __restrict__ Qbf, const unsigned short* __restrict__ Kbf,
    const unsigned short* __restrict__ VTbf, float* __restrict__ Og,
    float* __restrict__ Ag) {

  // bijective XCD swizzle: 2048 = 8 * 256
  int wg = ((blockIdx.x & 7) << 8) | (blockIdx.x >> 3);
  int qt = wg & 31, bh = wg >> 5;
  int h = bh & 15, b = bh >> 4;

  int tid = threadIdx.x, lane = tid & 63, w = tid >> 6;
  int g = lane >> 4, r16 = lane & 15;

  __shared__ __align__(16) unsigned short Qb[64][64];
  __shared__ __align__(16) unsigned short Kb[2][64][64];
  __shared__ __align__(16) unsigned short Vb[2][64][64];
  __shared__ __align__(16) unsigned short Pb[4][16][72];

  const unsigned short* qg = Qbf + ((size_t)bh * 2048 + qt * 64 + w * 16) * 64;
  const unsigned short* kg = Kbf + (size_t)bh * 2048 * 64 + (size_t)(w * 16) * 64;
  const unsigned short* vg = VTbf + (size_t)bh * 64 * 2048 + (size_t)(w * 16) * 2048;

  // ---- prologue: Q + first two K-pairs into the 4-slot ring ----
  stage16(qg, 64, &Qb[w * 16][0], lane);                       // 2 loads
  stage16(kg,            64, &Kb[0][w * 16][0], lane);         // pair A: ch 0
  stage16(kg + 4096,     64, &Kb[1][w * 16][0], lane);         //         ch 1
  stage16(kg + 2 * 4096, 64, &Vb[0][w * 16][0], lane);         // pair B: ch 2
  stage16(kg + 3 * 4096, 64, &Vb[1][w * 16][0], lane);         //         ch 3
  asm volatile("s_waitcnt vmcnt(8)" ::: "memory");             // Q done
  __builtin_amdgcn_s_barrier();

  short8 qf0 = frag(&Qb[0][0], w * 16 + r16, g * 16);
  short8 qf1 = frag(&Qb[0][0], w * 16 + r16, 64 + g * 16);

  // ---------------- phase 1: row sums, 2 chunks/iter ----------------
  float lsum = 0.0f;
  for (int ii = 0; ii < 16; ++ii) {
    const int hi = ii & 1;
    const unsigned short* sA = hi ? &Vb[0][0][0] : &Kb[0][0][0];
    const unsigned short* sB = hi ? &Vb[1][0][0] : &Kb[1][0][0];

    if (ii < 15) {
      asm volatile("s_waitcnt vmcnt(4)" ::: "memory");   // this iter's pair ready
    } else {
      asm volatile("s_waitcnt vmcnt(0)" ::: "memory");
    }
    __builtin_amdgcn_s_barrier();

    f32x4 st[8];
    __builtin_amdgcn_s_setprio(1);
#pragma unroll
    for (int t = 0; t < 4; ++t) {
      short8 kf0 = frag(sA, t * 16 + r16, g * 16);
      short8 kf1 = frag(sA, t * 16 + r16, 64 + g * 16);
      f32x4 z = {0.f, 0.f, 0.f, 0.f};
      z = MFMA16(kf0, qf0, z);      // swapped: A=K (s rows), B=Q (q cols)
      z = MFMA16(kf1, qf1, z);
      st[t] = z;
    }
#pragma unroll
    for (int t = 0; t < 4; ++t) {
      short8 kf0 = frag(sB, t * 16 + r16, g * 16);
      short8 kf1 = frag(sB, t * 16 + r16, 64 + g * 16);
      f32x4 z = {0.f, 0.f, 0.f, 0.f};
      z = MFMA16(kf0, qf0, z);
      z = MFMA16(kf1, qf1, z);
      st[t + 4] = z;
    }
    __builtin_amdgcn_s_setprio(0);

    float acc = 0.f;
#pragma unroll
    for (int t = 0; t < 8; ++t) {
      float e0 = __builtin_amdgcn_exp2f(st[t][0]) + __builtin_amdgcn_exp2f(st[t][1]);
      float e1 = __builtin_amdgcn_exp2f(st[t][2]) + __builtin_amdgcn_exp2f(st[t][3]);
      acc += e0 + e1;
    }
    lsum += acc;

    __builtin_amdgcn_s_barrier();    // all waves done reading this pair's slots

    if (ii < 14) {
      const unsigned short* nk = kg + (size_t)(2 * ii + 4) * 4096;
      unsigned short* dA = hi ? &Vb[0][w * 16][0] : &Kb[0][w * 16][0];
      unsigned short* dB = hi ? &Vb[1][w * 16][0] : &Kb[1][w * 16][0];
      stage16(nk,        64, dA, lane);
      stage16(nk + 4096, 64, dB, lane);
    }
  }
  lsum += __shfl_xor(lsum, 16, 64);
  lsum += __shfl_xor(lsum, 32, 64);
  float rinv = 1.0f / lsum;          // per-lane q = qt*64 + w*16 + r16

  // ---------------- phase 2: P write + PV ----------------
  f32x4 oacc[4];
#pragma unroll
  for (int t = 0; t < 4; ++t) oacc[t] = (f32x4){0.f, 0.f, 0.f, 0.f};

  stage16(kg, 64, &Kb[0][w * 16][0], lane);
  stage16(vg, 2048, &Vb[0][w * 16][0], lane);
  asm volatile("s_waitcnt vmcnt(0)" ::: "memory");
  __builtin_amdgcn_s_barrier();
  int cur = 0;

  // coalesced-store geometry: inst i covers q-rows 4i+(lane>>4), s-slice (lane&15)*4
  float* aW = Ag + ((size_t)bh * 2048 + (size_t)(qt * 64 + w * 16)) * 2048;
  const int sra = lane >> 4;         // row sub-index 0..3
  const int src4 = (lane & 15) * 4;  // s offset within 64-chunk

  for (int ch = 0; ch < 32; ++ch) {
    if (ch < 31) {
      stage16(kg + (size_t)(ch + 1) * 4096, 64, &Kb[cur ^ 1][w * 16][0], lane);
      stage16(vg + (size_t)(ch + 1) * 64, 2048, &Vb[cur ^ 1][w * 16][0], lane);
    }
    f32x4 st[4];
    __builtin_amdgcn_s_setprio(1);
#pragma unroll
    for (int t = 0; t < 4; ++t) {
      short8 kf0 = frag(&Kb[cur][0][0], t * 16 + r16, g * 16);
      short8 kf1 = frag(&Kb[cur][0][0], t * 16 + r16, 64 + g * 16);
      f32x4 z = {0.f, 0.f, 0.f, 0.f};
      z = MFMA16(kf0, qf0, z);
      z = MFMA16(kf1, qf1, z);
      st[t] = z;
    }
    __builtin_amdgcn_s_setprio(0);

    // lane holds P[s = ch*64 + t*16 + 4g + r][q = r16]; normalize -> bf16 LDS only
#pragma unroll
    for (int t = 0; t < 4; ++t) {
      f32x4 p;
#pragma unroll
      for (int r = 0; r < 4; ++r)
        p[r] = __builtin_amdgcn_exp2f(st[t][r]) * rinv;
      u16x4 pb = { bf(p[0]), bf(p[1]), bf(p[2]), bf(p[3]) };
      *(u16x4*)&Pb[w][r16][t * 16 + 4 * g] = pb;
    }

    // attn_map stores, store-order re-read: 4 insts x (4 rows x 256B contiguous)
#pragma unroll
    for (int i = 0; i < 4; ++i) {
      int row = 4 * i + sra;
      u16x4 pb4 = *(const u16x4*)&Pb[w][row][src4];
      f32x4 o = { bf2f(pb4[0]), bf2f(pb4[1]), bf2f(pb4[2]), bf2f(pb4[3]) };
      __builtin_nontemporal_store(o, (f32x4*)(aW + (size_t)row * 2048 + ch * 64 + src4));
    }

    __builtin_amdgcn_s_setprio(1);
#pragma unroll
    for (int c = 0; c < 2; ++c) {
      short8 pa = *(const short8*)((const char*)&Pb[w][r16][0] + c * 64 + g * 16);
#pragma unroll
      for (int t = 0; t < 4; ++t) {
        short8 vf = frag(&Vb[cur][0][0], t * 16 + r16, c * 64 + g * 16);
        oacc[t] = MFMA16(pa, vf, oacc[t]);
      }
    }
    __builtin_amdgcn_s_setprio(0);

    // wait only the 4 global_load_lds (oldest); leave the 4 nt stores in flight
    asm volatile("s_waitcnt vmcnt(4)" ::: "memory");
    __builtin_amdgcn_s_barrier();
    cur ^= 1;
  }

  // v out: [b, l, h, d]; lane (g,r16) holds rows q=4g+r, col d=t*16+r16
  float* op = Og + (((size_t)b * 2048 + (size_t)(qt * 64 + w * 16 + 4 * g)) * 16 + h) * 64;
#pragma unroll
  for (int t = 0; t < 4; ++t)
#pragma unroll
    for (int r = 0; r < 4; ++r)
      op[(size_t)r * 1024 + t * 16 + r16] = oacc[t][r];
}

// ============================ fp32 fallback ============================

__global__ __launch_bounds__(256, 2) void attn_fused(
    const float* __restrict__ Qg, const float* __restrict__ Kg,
    const float* __restrict__ Vg, float* __restrict__ Og,
    float* __restrict__ Ag) {

  const int qt = blockIdx.x & 31;
  const int bh = blockIdx.x >> 5;
  const int h  = bh & 15;
  const int b  = bh >> 4;

  const int tid  = threadIdx.x;
  const int lane = tid & 63;
  const int w    = tid >> 6;
  const int g    = lane >> 4;
  const int r16  = lane & 15;

  __shared__ __align__(16) unsigned short Qbuf[64][72];
  __shared__ __align__(16) unsigned short Kbuf[64][72];
  __shared__ __align__(16) unsigned short VT[64][68];
  __shared__ __align__(16) unsigned short Pbuf[4][16][72];

  const size_t inbase = (size_t)b * (2048u * 1024u) + (size_t)h * 64u;
  const int q0 = qt << 6;

  const int srow = tid >> 2;
  const int sd0  = (tid & 3) << 4;

  {
    const float sc = 0.18033688011112042f;
    const float* gp = Qg + inbase + (size_t)(q0 + srow) * 1024u + sd0;
    float4 va = *(const float4*)(gp + 0);
    float4 vb = *(const float4*)(gp + 4);
    float4 vc = *(const float4*)(gp + 8);
    float4 vd = *(const float4*)(gp + 12);
    unsigned short* dst = &Qbuf[srow][sd0];
    dst[0]=f2bf(va.x*sc); dst[1]=f2bf(va.y*sc); dst[2]=f2bf(va.z*sc); dst[3]=f2bf(va.w*sc);
    dst[4]=f2bf(vb.x*sc); dst[5]=f2bf(vb.y*sc); dst[6]=f2bf(vb.z*sc); dst[7]=f2bf(vb.w*sc);
    dst[8]=f2bf(vc.x*sc); dst[9]=f2bf(vc.y*sc); dst[10]=f2bf(vc.z*sc); dst[11]=f2bf(vc.w*sc);
    dst[12]=f2bf(vd.x*sc); dst[13]=f2bf(vd.y*sc); dst[14]=f2bf(vd.z*sc); dst[15]=f2bf(vd.w*sc);
  }
  __syncthreads();

  const short8 qf0 = *(const short8*)&Qbuf[w*16 + r16][g*8];
  const short8 qf1 = *(const short8*)&Qbuf[w*16 + r16][32 + g*8];

  f32x4 mrow = { -3e38f, -3e38f, -3e38f, -3e38f };
  f32x4 lrow = { 0.f, 0.f, 0.f, 0.f };

  for (int ch = 0; ch < 32; ++ch) {
    __syncthreads();
    {
      const float* gp = Kg + inbase + (size_t)(ch*64 + srow) * 1024u + sd0;
      float4 va = *(const float4*)(gp + 0);
      float4 vb = *(const float4*)(gp + 4);
      float4 vc = *(const float4*)(gp + 8);
      float4 vd = *(const float4*)(gp + 12);
      unsigned short* dst = &Kbuf[srow][sd0];
      dst[0]=f2bf(va.x); dst[1]=f2bf(va.y); dst[2]=f2bf(va.z); dst[3]=f2bf(va.w);
      dst[4]=f2bf(vb.x); dst[5]=f2bf(vb.y); dst[6]=f2bf(vb.z); dst[7]=f2bf(vb.w);
      dst[8]=f2bf(vc.x); dst[9]=f2bf(vc.y); dst[10]=f2bf(vc.z); dst[11]=f2bf(vc.w);
      dst[12]=f2bf(vd.x); dst[13]=f2bf(vd.y); dst[14]=f2bf(vd.z); dst[15]=f2bf(vd.w);
    }
    __syncthreads();

    f32x4 st[4];
#pragma unroll
    for (int t = 0; t < 4; ++t) {
      const short8 kf0 = *(const short8*)&Kbuf[t*16 + r16][g*8];
      const short8 kf1 = *(const short8*)&Kbuf[t*16 + r16][32 + g*8];
      f32x4 z = {0.f, 0.f, 0.f, 0.f};
      z = MFMA16(qf0, kf0, z);
      z = MFMA16(qf1, kf1, z);
      st[t] = z;
    }

    f32x4 cm = st[0];
#pragma unroll
    for (int t = 1; t < 4; ++t)
#pragma unroll
      for (int r = 0; r < 4; ++r) cm[r] = fmaxf(cm[r], st[t][r]);
#pragma unroll
    for (int i = 1; i < 16; i <<= 1)
#pragma unroll
      for (int r = 0; r < 4; ++r) cm[r] = fmaxf(cm[r], __shfl_xor(cm[r], i, 64));

    f32x4 mn, corr, sum = {0.f, 0.f, 0.f, 0.f};
#pragma unroll
    for (int r = 0; r < 4; ++r) {
      mn[r]   = fmaxf(mrow[r], cm[r]);
      corr[r] = exp2f(mrow[r] - mn[r]);
    }
#pragma unroll
    for (int t = 0; t < 4; ++t)
#pragma unroll
      for (int r = 0; r < 4; ++r) sum[r] += exp2f(st[t][r] - mn[r]);
#pragma unroll
    for (int i = 1; i < 16; i <<= 1)
#pragma unroll
      for (int r = 0; r < 4; ++r) sum[r] += __shfl_xor(sum[r], i, 64);
#pragma unroll
    for (int r = 0; r < 4; ++r) {
      lrow[r] = lrow[r] * corr[r] + sum[r];
      mrow[r] = mn[r];
    }
  }

  f32x4 rinv;
#pragma unroll
  for (int r = 0; r < 4; ++r) rinv[r] = 1.0f / lrow[r];

  f32x4 oacc[4];
#pragma unroll
  for (int t = 0; t < 4; ++t) oacc[t] = (f32x4){0.f, 0.f, 0.f, 0.f};

  float* aRow = Ag + ((size_t)bh * 2048u + (size_t)(q0 + w*16 + 4*g)) * 2048u;

  for (int ch = 0; ch < 32; ++ch) {
    __syncthreads();
    {
      const float* gp = Kg + inbase + (size_t)(ch*64 + srow) * 1024u + sd0;
      float4 va = *(const float4*)(gp + 0);
      float4 vb = *(const float4*)(gp + 4);
      float4 vc = *(const float4*)(gp + 8);
      float4 vd = *(const float4*)(gp + 12);
      unsigned short* dst = &Kbuf[srow][sd0];
      dst[0]=f2bf(va.x); dst[1]=f2bf(va.y); dst[2]=f2bf(va.z); dst[3]=f2bf(va.w);
      dst[4]=f2bf(vb.x); dst[5]=f2bf(vb.y); dst[6]=f2bf(vb.z); dst[7]=f2bf(vb.w);
      dst[8]=f2bf(vc.x); dst[9]=f2bf(vc.y); dst[10]=f2bf(vc.z); dst[11]=f2bf(vc.w);
      dst[12]=f2bf(vd.x); dst[13]=f2bf(vd.y); dst[14]=f2bf(vd.z); dst[15]=f2bf(vd.w);
    }
    {
      const float* gp = Vg + inbase + (size_t)(ch*64 + lane) * 1024u + (size_t)(w*16);
      float4 va = *(const float4*)(gp + 0);
      float4 vb = *(const float4*)(gp + 4);
      float4 vc = *(const float4*)(gp + 8);
      float4 vd = *(const float4*)(gp + 12);
      const int dbase = w * 16;
      VT[dbase+ 0][lane]=f2bf(va.x); VT[dbase+ 1][lane]=f2bf(va.y);
      VT[dbase+ 2][lane]=f2bf(va.z); VT[dbase+ 3][lane]=f2bf(va.w);
      VT[dbase+ 4][lane]=f2bf(vb.x); VT[dbase+ 5][lane]=f2bf(vb.y);
      VT[dbase+ 6][lane]=f2bf(vb.z); VT[dbase+ 7][lane]=f2bf(vb.w);
      VT[dbase+ 8][lane]=f2bf(vc.x); VT[dbase+ 9][lane]=f2bf(vc.y);
      VT[dbase+10][lane]=f2bf(vc.z); VT[dbase+11][lane]=f2bf(vc.w);
      VT[dbase+12][lane]=f2bf(vd.x); VT[dbase+13][lane]=f2bf(vd.y);
      VT[dbase+14][lane]=f2bf(vd.z); VT[dbase+15][lane]=f2bf(vd.w);
    }
    __syncthreads();

    f32x4 st[4];
#pragma unroll
    for (int t = 0; t < 4; ++t) {
      const short8 kf0 = *(const short8*)&Kbuf[t*16 + r16][g*8];
      const short8 kf1 = *(const short8*)&Kbuf[t*16 + r16][32 + g*8];
      f32x4 z = {0.f, 0.f, 0.f, 0.f};
      z = MFMA16(qf0, kf0, z);
      z = MFMA16(qf1, kf1, z);
      st[t] = z;
    }

#pragma unroll
    for (int t = 0; t < 4; ++t) {
#pragma unroll
      for (int r = 0; r < 4; ++r) {
        float p = exp2f(st[t][r] - mrow[r]) * rinv[r];
        aRow[(size_t)r * 2048u + (size_t)(ch*64 + t*16 + r16)] = p;
        Pbuf[w][4*g + r][t*16 + r16] = f2bf(p);
      }
    }

#pragma unroll
    for (int c = 0; c < 2; ++c) {
      const short8 pa = *(const short8*)&Pbuf[w][r16][c*32 + g*8];
#pragma unroll
      for (int t = 0; t < 4; ++t) {
        const unsigned short* vp = &VT[t*16 + r16][c*32 + g*8];
        short4v lo = *(const short4v*)vp;
        short4v hi = *(const short4v*)(vp + 4);
        short8 vbf = { lo[0], lo[1], lo[2], lo[3], hi[0], hi[1], hi[2], hi[3] };
        oacc[t] = MFMA16(pa, vbf, oacc[t]);
      }
    }
  }

  float* op = Og + (((size_t)b * 2048u + (size_t)(q0 + w*16 + 4*g)) * 16u + (size_t)h) * 64u;
#pragma unroll
  for (int t = 0; t < 4; ++t)
#pragma unroll
    for (int r = 0; r < 4; ++r)
      op[(size_t)r * 1024u + (size_t)(t*16 + r16)] = oacc[t][r];
}

// ============================ launcher ============================

extern "C" void kernel_launch(void* const* d_in, const int* in_sizes, int n_in,
                              void* d_out, int out_size, void* d_ws, size_t ws_size,
                              hipStream_t stream) {
  const float* Q = (const float*)d_in[0];
  const float* K = (const float*)d_in[1];
  const float* V = (const float*)d_in[2];
  float* Og = (float*)d_out;               // v: 4*2048*16*64 = 8388608
  float* Ag = (float*)d_out + 8388608;     // attn_map: 4*16*2048*2048

  const size_t NEED = 3ull * 8388608ull * 2ull;  // Qbf + Kbf + VTbf = 50331648 B
  if (ws_size >= NEED) {
    unsigned short* Qbf  = (unsigned short*)d_ws;
    unsigned short* Kbf  = Qbf + 8388608;
    unsigned short* VTbf = Kbf + 8388608;
    conv_all<<<dim3(10240), dim3(256), 0, stream>>>(Q, K, V, Qbf, Kbf, VTbf);
    attn_main<<<dim3(2048), dim3(256), 0, stream>>>(Qbf, Kbf, VTbf, Og, Ag);
  } else {
    attn_fused<<<dim3(2048), dim3(256), 0, stream>>>(Q, K, V, Og, Ag);
  }
}

// Round 7
// 237.520 us; speedup vs baseline: 5.2880x; 1.0365x over previous
//
#include <hip/hip_runtime.h>
#include <hip/hip_bf16.h>

// ResAttention fused forward: out = (v [B,L,H,D] , attn_map [B,H,L,S]), fp32.
// B=4, L=S=2048, H=16, E=D=64.
// Fast path (needs ws >= 50331648 B):
//   conv_all: K -> bf16 [b,h,l,e]; V -> bf16 transposed [b,h,d,s]
//   attn_main: 512-thread block (8 waves) per (b,h,128 q-rows); wave owns 16 q.
//     prologue: block converts its own Q fp32->bf16 (pre-scaled 1/8*log2e) in LDS.
//     phase 1: row sums of exp2(scores), 4-slot K ring, 2 chunks/iter, vmcnt(2).
//     phase 2: recompute scores, P->bf16 per-wave LDS; attn_map written via
//              store-order re-read (4 insts x 4 rows x 256B contiguous, the R6
//              win); PV MFMA; K/V dbuf with vmcnt(4) leaving nt stores in flight.

typedef __attribute__((ext_vector_type(4)))  float  f32x4;
typedef __attribute__((ext_vector_type(8)))  short  short8;
typedef __attribute__((ext_vector_type(4)))  short  short4v;
typedef __attribute__((ext_vector_type(4)))  unsigned short u16x4;

__device__ __forceinline__ unsigned short bf(float x) {
  return __builtin_bit_cast(unsigned short, __float2bfloat16(x));
}

__device__ __forceinline__ float bf2f(unsigned short u) {
  return __builtin_bit_cast(float, (unsigned int)u << 16);
}

__device__ __forceinline__ unsigned short f2bf(float f) {
  unsigned int u = __builtin_bit_cast(unsigned int, f);
  return (unsigned short)((u + 0x7FFFu + ((u >> 16) & 1u)) >> 16);  // RNE
}

#define MFMA16(A, Bv, C) __builtin_amdgcn_mfma_f32_16x16x32_bf16(A, Bv, C, 0, 0, 0)

// ============================ prologue kernel ============================

__global__ __launch_bounds__(256) void conv_all(const float* __restrict__ K,
                                                const float* __restrict__ V,
                                                unsigned short* __restrict__ Kbf,
                                                unsigned short* __restrict__ VTbf) {
  __shared__ unsigned short T[64][68];
  if (blockIdx.x < 4096) {
    int idx = blockIdx.x * 256 + threadIdx.x;   // 2^20 total
    int e0 = (idx & 7) << 3;
    int h  = (idx >> 3) & 15;
    int l  = (idx >> 7) & 2047;
    int b  = idx >> 18;
    const float* src = K + (((size_t)(b * 2048 + l)) * 16 + h) * 64 + e0;
    unsigned short* dst = Kbf + (((size_t)(b * 16 + h)) * 2048 + l) * 64 + e0;
    float4 a = *(const float4*)src;
    float4 c = *(const float4*)(src + 4);
    u16x4 o0 = { bf(a.x), bf(a.y), bf(a.z), bf(a.w) };
    u16x4 o1 = { bf(c.x), bf(c.y), bf(c.z), bf(c.w) };
    *(u16x4*)dst = o0;
    *(u16x4*)(dst + 4) = o1;
  } else {
    int bid = blockIdx.x - 4096;     // (b*16+h)*32 + sc
    int sc = bid & 31, bh = bid >> 5;
    int h = bh & 15, b = bh >> 4;
    int t = threadIdx.x;
    int srow = t >> 2, d0 = (t & 3) << 4;
    const float* src = V + (((size_t)(b * 2048 + sc * 64 + srow)) * 16 + h) * 64 + d0;
    float4 v0 = *(const float4*)(src + 0);
    float4 v1 = *(const float4*)(src + 4);
    float4 v2 = *(const float4*)(src + 8);
    float4 v3 = *(const float4*)(src + 12);
    T[d0+ 0][srow]=bf(v0.x); T[d0+ 1][srow]=bf(v0.y); T[d0+ 2][srow]=bf(v0.z); T[d0+ 3][srow]=bf(v0.w);
    T[d0+ 4][srow]=bf(v1.x); T[d0+ 5][srow]=bf(v1.y); T[d0+ 6][srow]=bf(v1.z); T[d0+ 7][srow]=bf(v1.w);
    T[d0+ 8][srow]=bf(v2.x); T[d0+ 9][srow]=bf(v2.y); T[d0+10][srow]=bf(v2.z); T[d0+11][srow]=bf(v2.w);
    T[d0+12][srow]=bf(v3.x); T[d0+13][srow]=bf(v3.y); T[d0+14][srow]=bf(v3.z); T[d0+15][srow]=bf(v3.w);
    __syncthreads();
    int d = t >> 2, s0 = (t & 3) << 4;
    unsigned short* dst = VTbf + ((size_t)bh * 64 + d) * 2048 + sc * 64 + s0;
#pragma unroll
    for (int j = 0; j < 16; j += 4) {
      u16x4 x = { T[d][s0 + j], T[d][s0 + j + 1], T[d][s0 + j + 2], T[d][s0 + j + 3] };
      *(u16x4*)(dst + j) = x;
    }
  }
}

// ============================ main kernel ============================

__device__ __forceinline__ void gll16(const void* g, void* l) {
  __builtin_amdgcn_global_load_lds(
      (const __attribute__((address_space(1))) unsigned int*)g,
      (__attribute__((address_space(3))) unsigned int*)l, 16, 0, 0);
}

// Stage 8 rows (this wave's eighth of a 64x64 bf16 tile) into LDS,
// XOR-swizzled via pre-swizzled per-lane global source (linear LDS dest).
// One global_load_lds per lane. gsrc pre-offset to this wave's first row.
__device__ __forceinline__ void stage8(const unsigned short* gsrc, int rowStride,
                                       unsigned short* dstRow0, int lane) {
  int rr = lane >> 3;                     // row within 8-row group (= row&7)
  int cc = ((lane & 7) ^ rr) << 3;        // swizzled source column (elements)
  gll16(gsrc + (size_t)rr * rowStride + cc, dstRow0);
}

// Swizzled b128 fragment read: data column colb (bytes) of tile row `row`.
__device__ __forceinline__ short8 frag(const unsigned short* tile, int row, int colb) {
  return *(const short8*)((const char*)tile + row * 128 + (colb ^ ((row & 7) << 4)));
}

__global__ __launch_bounds__(512, 2) void attn_main(
    const float* __restrict__ Qf, const unsigned short* __restrict__ Kbf,
    const unsigned short* __restrict__ VTbf, float* __restrict__ Og,
    float* __restrict__ Ag) {

  // bijective XCD swizzle: 1024 = 8 * 128
  int wg = ((blockIdx.x & 7) << 7) | (blockIdx.x >> 3);
  int qt = wg & 15, bh = wg >> 4;      // 16 q-tiles of 128 rows
  int h = bh & 15, b = bh >> 4;

  int tid = threadIdx.x, lane = tid & 63, w = tid >> 6;   // 8 waves
  int g = lane >> 4, r16 = lane & 15;
  int q0 = qt * 128;

  __shared__ __align__(16) unsigned short Qb[128][64];     // 16 KB, unswizzled
  __shared__ __align__(16) unsigned short Kb[2][64][64];   // 16 KB
  __shared__ __align__(16) unsigned short Vb[2][64][64];   // 16 KB
  __shared__ __align__(16) unsigned short Pb[8][16][72];   // 18 KB, per-wave P

  const unsigned short* kg = Kbf + (size_t)bh * 2048 * 64 + (size_t)(w * 8) * 64;
  const unsigned short* vg = VTbf + (size_t)bh * 64 * 2048 + (size_t)(w * 8) * 2048;

  // ---- prologue: convert this block's Q fp32->bf16 (pre-scaled), stage K ring ----
  {
    const float sc = 0.18033688011112042f;  // (1/sqrt(64))*log2(e)
    int row = tid >> 2, c0 = (tid & 3) << 4;
    const float* qsrc = Qf + (((size_t)(b * 2048 + q0 + row)) * 16 + h) * 64 + c0;
    float4 qa = *(const float4*)(qsrc + 0);
    float4 qb = *(const float4*)(qsrc + 4);
    float4 qc = *(const float4*)(qsrc + 8);
    float4 qd = *(const float4*)(qsrc + 12);
    // K ring prefetch: ch 0..3 (1 gll per wave per tile)
    stage8(kg,            64, &Kb[0][w * 8][0], lane);
    stage8(kg + 4096,     64, &Kb[1][w * 8][0], lane);
    stage8(kg + 2 * 4096, 64, &Vb[0][w * 8][0], lane);
    stage8(kg + 3 * 4096, 64, &Vb[1][w * 8][0], lane);
    unsigned short* qdst = &Qb[row][c0];
    u16x4 o0 = { bf(qa.x*sc), bf(qa.y*sc), bf(qa.z*sc), bf(qa.w*sc) };
    u16x4 o1 = { bf(qb.x*sc), bf(qb.y*sc), bf(qb.z*sc), bf(qb.w*sc) };
    u16x4 o2 = { bf(qc.x*sc), bf(qc.y*sc), bf(qc.z*sc), bf(qc.w*sc) };
    u16x4 o3 = { bf(qd.x*sc), bf(qd.y*sc), bf(qd.z*sc), bf(qd.w*sc) };
    *(u16x4*)(qdst + 0) = o0;  *(u16x4*)(qdst + 4)  = o1;
    *(u16x4*)(qdst + 8) = o2;  *(u16x4*)(qdst + 12) = o3;
  }
  asm volatile("s_waitcnt lgkmcnt(0)" ::: "memory");   // own Qb writes flushed
  __builtin_amdgcn_s_barrier();                        // all Qb writes visible

  // Q fragments (plain layout; one-time read, conflicts negligible)
  short8 qf0 = *(const short8*)((const char*)&Qb[w * 16 + r16][0] + g * 16);
  short8 qf1 = *(const short8*)((const char*)&Qb[w * 16 + r16][0] + 64 + g * 16);

  // ---------------- phase 1: row sums, 2 chunks/iter ----------------
  float lsum = 0.0f;
  for (int ii = 0; ii < 16; ++ii) {
    const int hsel = ii & 1;
    const unsigned short* sA = hsel ? &Vb[0][0][0] : &Kb[0][0][0];
    const unsigned short* sB = hsel ? &Vb[1][0][0] : &Kb[1][0][0];

    if (ii < 15) {
      asm volatile("s_waitcnt vmcnt(2)" ::: "memory");   // this iter's pair ready
    } else {
      asm volatile("s_waitcnt vmcnt(0)" ::: "memory");
    }
    __builtin_amdgcn_s_barrier();

    f32x4 st[8];
    __builtin_amdgcn_s_setprio(1);
#pragma unroll
    for (int t = 0; t < 4; ++t) {
      short8 kf0 = frag(sA, t * 16 + r16, g * 16);
      short8 kf1 = frag(sA, t * 16 + r16, 64 + g * 16);
      f32x4 z = {0.f, 0.f, 0.f, 0.f};
      z = MFMA16(kf0, qf0, z);      // swapped: A=K (s rows), B=Q (q cols)
      z = MFMA16(kf1, qf1, z);
      st[t] = z;
    }
#pragma unroll
    for (int t = 0; t < 4; ++t) {
      short8 kf0 = frag(sB, t * 16 + r16, g * 16);
      short8 kf1 = frag(sB, t * 16 + r16, 64 + g * 16);
      f32x4 z = {0.f, 0.f, 0.f, 0.f};
      z = MFMA16(kf0, qf0, z);
      z = MFMA16(kf1, qf1, z);
      st[t + 4] = z;
    }
    __builtin_amdgcn_s_setprio(0);

    float acc = 0.f;
#pragma unroll
    for (int t = 0; t < 8; ++t) {
      float e0 = __builtin_amdgcn_exp2f(st[t][0]) + __builtin_amdgcn_exp2f(st[t][1]);
      float e1 = __builtin_amdgcn_exp2f(st[t][2]) + __builtin_amdgcn_exp2f(st[t][3]);
      acc += e0 + e1;
    }
    lsum += acc;

    __builtin_amdgcn_s_barrier();    // all waves done reading this pair's slots

    if (ii < 14) {
      const unsigned short* nk = kg + (size_t)(2 * ii + 4) * 4096;
      unsigned short* dA = hsel ? &Vb[0][w * 8][0] : &Kb[0][w * 8][0];
      unsigned short* dB = hsel ? &Vb[1][w * 8][0] : &Kb[1][w * 8][0];
      stage8(nk,        64, dA, lane);
      stage8(nk + 4096, 64, dB, lane);
    }
  }
  lsum += __shfl_xor(lsum, 16, 64);
  lsum += __shfl_xor(lsum, 32, 64);
  float rinv = 1.0f / lsum;          // per-lane q = q0 + w*16 + r16

  // ---------------- phase 2: P write + PV ----------------
  f32x4 oacc[4];
#pragma unroll
  for (int t = 0; t < 4; ++t) oacc[t] = (f32x4){0.f, 0.f, 0.f, 0.f};

  stage8(kg, 64, &Kb[0][w * 8][0], lane);
  stage8(vg, 2048, &Vb[0][w * 8][0], lane);
  asm volatile("s_waitcnt vmcnt(0)" ::: "memory");
  __builtin_amdgcn_s_barrier();
  int cur = 0;

  // coalesced-store geometry: inst i covers q-rows 4i+(lane>>4), s-slice (lane&15)*4
  float* aW = Ag + ((size_t)bh * 2048 + (size_t)(q0 + w * 16)) * 2048;
  const int sra = lane >> 4;         // row sub-index 0..3
  const int src4 = (lane & 15) * 4;  // s offset within 64-chunk

  for (int ch = 0; ch < 32; ++ch) {
    if (ch < 31) {
      stage8(kg + (size_t)(ch + 1) * 4096, 64, &Kb[cur ^ 1][w * 8][0], lane);
      stage8(vg + (size_t)(ch + 1) * 64, 2048, &Vb[cur ^ 1][w * 8][0], lane);
    }
    f32x4 st[4];
    __builtin_amdgcn_s_setprio(1);
#pragma unroll
    for (int t = 0; t < 4; ++t) {
      short8 kf0 = frag(&Kb[cur][0][0], t * 16 + r16, g * 16);
      short8 kf1 = frag(&Kb[cur][0][0], t * 16 + r16, 64 + g * 16);
      f32x4 z = {0.f, 0.f, 0.f, 0.f};
      z = MFMA16(kf0, qf0, z);
      z = MFMA16(kf1, qf1, z);
      st[t] = z;
    }
    __builtin_amdgcn_s_setprio(0);

    // lane holds P[s = ch*64 + t*16 + 4g + r][q = r16]; normalize -> bf16 LDS only
#pragma unroll
    for (int t = 0; t < 4; ++t) {
      f32x4 p;
#pragma unroll
      for (int r = 0; r < 4; ++r)
        p[r] = __builtin_amdgcn_exp2f(st[t][r]) * rinv;
      u16x4 pb = { bf(p[0]), bf(p[1]), bf(p[2]), bf(p[3]) };
      *(u16x4*)&Pb[w][r16][t * 16 + 4 * g] = pb;
    }

    // attn_map stores, store-order re-read: 4 insts x (4 rows x 256B contiguous)
#pragma unroll
    for (int i = 0; i < 4; ++i) {
      int row = 4 * i + sra;
      u16x4 pb4 = *(const u16x4*)&Pb[w][row][src4];
      f32x4 o = { bf2f(pb4[0]), bf2f(pb4[1]), bf2f(pb4[2]), bf2f(pb4[3]) };
      __builtin_nontemporal_store(o, (f32x4*)(aW + (size_t)row * 2048 + ch * 64 + src4));
    }

    __builtin_amdgcn_s_setprio(1);
#pragma unroll
    for (int c = 0; c < 2; ++c) {
      short8 pa = *(const short8*)((const char*)&Pb[w][r16][0] + c * 64 + g * 16);
#pragma unroll
      for (int t = 0; t < 4; ++t) {
        short8 vf = frag(&Vb[cur][0][0], t * 16 + r16, c * 64 + g * 16);
        oacc[t] = MFMA16(pa, vf, oacc[t]);
      }
    }
    __builtin_amdgcn_s_setprio(0);

    // wait only the 2 global_load_lds (oldest); leave the 4 nt stores in flight
    asm volatile("s_waitcnt vmcnt(4)" ::: "memory");
    __builtin_amdgcn_s_barrier();
    cur ^= 1;
  }

  // v out: [b, l, h, d]; lane (g,r16) holds rows q=4g+r, col d=t*16+r16
  float* op = Og + (((size_t)b * 2048 + (size_t)(q0 + w * 16 + 4 * g)) * 16 + h) * 64;
#pragma unroll
  for (int t = 0; t < 4; ++t)
#pragma unroll
    for (int r = 0; r < 4; ++r)
      op[(size_t)r * 1024 + t * 16 + r16] = oacc[t][r];
}

// ============================ fp32 fallback ============================

__global__ __launch_bounds__(256, 2) void attn_fused(
    const float* __restrict__ Qg, const float* __restrict__ Kg,
    const float* __restrict__ Vg, float* __restrict__ Og,
    float* __restrict__ Ag) {

  const int qt = blockIdx.x & 31;
  const int bh = blockIdx.x >> 5;
  const int h  = bh & 15;
  const int b  = bh >> 4;

  const int tid  = threadIdx.x;
  const int lane = tid & 63;
  const int w    = tid >> 6;
  const int g    = lane >> 4;
  const int r16  = lane & 15;

  __shared__ __align__(16) unsigned short Qbuf[64][72];
  __shared__ __align__(16) unsigned short Kbuf[64][72];
  __shared__ __align__(16) unsigned short VT[64][68];
  __shared__ __align__(16) unsigned short Pbuf[4][16][72];

  const size_t inbase = (size_t)b * (2048u * 1024u) + (size_t)h * 64u;
  const int q0 = qt << 6;

  const int srow = tid >> 2;
  const int sd0  = (tid & 3) << 4;

  {
    const float sc = 0.18033688011112042f;
    const float* gp = Qg + inbase + (size_t)(q0 + srow) * 1024u + sd0;
    float4 va = *(const float4*)(gp + 0);
    float4 vb = *(const float4*)(gp + 4);
    float4 vc = *(const float4*)(gp + 8);
    float4 vd = *(const float4*)(gp + 12);
    unsigned short* dst = &Qbuf[srow][sd0];
    dst[0]=f2bf(va.x*sc); dst[1]=f2bf(va.y*sc); dst[2]=f2bf(va.z*sc); dst[3]=f2bf(va.w*sc);
    dst[4]=f2bf(vb.x*sc); dst[5]=f2bf(vb.y*sc); dst[6]=f2bf(vb.z*sc); dst[7]=f2bf(vb.w*sc);
    dst[8]=f2bf(vc.x*sc); dst[9]=f2bf(vc.y*sc); dst[10]=f2bf(vc.z*sc); dst[11]=f2bf(vc.w*sc);
    dst[12]=f2bf(vd.x*sc); dst[13]=f2bf(vd.y*sc); dst[14]=f2bf(vd.z*sc); dst[15]=f2bf(vd.w*sc);
  }
  __syncthreads();

  const short8 qf0 = *(const short8*)&Qbuf[w*16 + r16][g*8];
  const short8 qf1 = *(const short8*)&Qbuf[w*16 + r16][32 + g*8];

  f32x4 mrow = { -3e38f, -3e38f, -3e38f, -3e38f };
  f32x4 lrow = { 0.f, 0.f, 0.f, 0.f };

  for (int ch = 0; ch < 32; ++ch) {
    __syncthreads();
    {
      const float* gp = Kg + inbase + (size_t)(ch*64 + srow) * 1024u + sd0;
      float4 va = *(const float4*)(gp + 0);
      float4 vb = *(const float4*)(gp + 4);
      float4 vc = *(const float4*)(gp + 8);
      float4 vd = *(const float4*)(gp + 12);
      unsigned short* dst = &Kbuf[srow][sd0];
      dst[0]=f2bf(va.x); dst[1]=f2bf(va.y); dst[2]=f2bf(va.z); dst[3]=f2bf(va.w);
      dst[4]=f2bf(vb.x); dst[5]=f2bf(vb.y); dst[6]=f2bf(vb.z); dst[7]=f2bf(vb.w);
      dst[8]=f2bf(vc.x); dst[9]=f2bf(vc.y); dst[10]=f2bf(vc.z); dst[11]=f2bf(vc.w);
      dst[12]=f2bf(vd.x); dst[13]=f2bf(vd.y); dst[14]=f2bf(vd.z); dst[15]=f2bf(vd.w);
    }
    __syncthreads();

    f32x4 st[4];
#pragma unroll
    for (int t = 0; t < 4; ++t) {
      const short8 kf0 = *(const short8*)&Kbuf[t*16 + r16][g*8];
      const short8 kf1 = *(const short8*)&Kbuf[t*16 + r16][32 + g*8];
      f32x4 z = {0.f, 0.f, 0.f, 0.f};
      z = MFMA16(qf0, kf0, z);
      z = MFMA16(qf1, kf1, z);
      st[t] = z;
    }

    f32x4 cm = st[0];
#pragma unroll
    for (int t = 1; t < 4; ++t)
#pragma unroll
      for (int r = 0; r < 4; ++r) cm[r] = fmaxf(cm[r], st[t][r]);
#pragma unroll
    for (int i = 1; i < 16; i <<= 1)
#pragma unroll
      for (int r = 0; r < 4; ++r) cm[r] = fmaxf(cm[r], __shfl_xor(cm[r], i, 64));

    f32x4 mn, corr, sum = {0.f, 0.f, 0.f, 0.f};
#pragma unroll
    for (int r = 0; r < 4; ++r) {
      mn[r]   = fmaxf(mrow[r], cm[r]);
      corr[r] = exp2f(mrow[r] - mn[r]);
    }
#pragma unroll
    for (int t = 0; t < 4; ++t)
#pragma unroll
      for (int r = 0; r < 4; ++r) sum[r] += exp2f(st[t][r] - mn[r]);
#pragma unroll
    for (int i = 1; i < 16; i <<= 1)
#pragma unroll
      for (int r = 0; r < 4; ++r) sum[r] += __shfl_xor(sum[r], i, 64);
#pragma unroll
    for (int r = 0; r < 4; ++r) {
      lrow[r] = lrow[r] * corr[r] + sum[r];
      mrow[r] = mn[r];
    }
  }

  f32x4 rinv;
#pragma unroll
  for (int r = 0; r < 4; ++r) rinv[r] = 1.0f / lrow[r];

  f32x4 oacc[4];
#pragma unroll
  for (int t = 0; t < 4; ++t) oacc[t] = (f32x4){0.f, 0.f, 0.f, 0.f};

  float* aRow = Ag + ((size_t)bh * 2048u + (size_t)(q0 + w*16 + 4*g)) * 2048u;

  for (int ch = 0; ch < 32; ++ch) {
    __syncthreads();
    {
      const float* gp = Kg + inbase + (size_t)(ch*64 + srow) * 1024u + sd0;
      float4 va = *(const float4*)(gp + 0);
      float4 vb = *(const float4*)(gp + 4);
      float4 vc = *(const float4*)(gp + 8);
      float4 vd = *(const float4*)(gp + 12);
      unsigned short* dst = &Kbuf[srow][sd0];
      dst[0]=f2bf(va.x); dst[1]=f2bf(va.y); dst[2]=f2bf(va.z); dst[3]=f2bf(va.w);
      dst[4]=f2bf(vb.x); dst[5]=f2bf(vb.y); dst[6]=f2bf(vb.z); dst[7]=f2bf(vb.w);
      dst[8]=f2bf(vc.x); dst[9]=f2bf(vc.y); dst[10]=f2bf(vc.z); dst[11]=f2bf(vc.w);
      dst[12]=f2bf(vd.x); dst[13]=f2bf(vd.y); dst[14]=f2bf(vd.z); dst[15]=f2bf(vd.w);
    }
    {
      const float* gp = Vg + inbase + (size_t)(ch*64 + lane) * 1024u + (size_t)(w*16);
      float4 va = *(const float4*)(gp + 0);
      float4 vb = *(const float4*)(gp + 4);
      float4 vc = *(const float4*)(gp + 8);
      float4 vd = *(const float4*)(gp + 12);
      const int dbase = w * 16;
      VT[dbase+ 0][lane]=f2bf(va.x); VT[dbase+ 1][lane]=f2bf(va.y);
      VT[dbase+ 2][lane]=f2bf(va.z); VT[dbase+ 3][lane]=f2bf(va.w);
      VT[dbase+ 4][lane]=f2bf(vb.x); VT[dbase+ 5][lane]=f2bf(vb.y);
      VT[dbase+ 6][lane]=f2bf(vb.z); VT[dbase+ 7][lane]=f2bf(vb.w);
      VT[dbase+ 8][lane]=f2bf(vc.x); VT[dbase+ 9][lane]=f2bf(vc.y);
      VT[dbase+10][lane]=f2bf(vc.z); VT[dbase+11][lane]=f2bf(vc.w);
      VT[dbase+12][lane]=f2bf(vd.x); VT[dbase+13][lane]=f2bf(vd.y);
      VT[dbase+14][lane]=f2bf(vd.z); VT[dbase+15][lane]=f2bf(vd.w);
    }
    __syncthreads();

    f32x4 st[4];
#pragma unroll
    for (int t = 0; t < 4; ++t) {
      const short8 kf0 = *(const short8*)&Kbuf[t*16 + r16][g*8];
      const short8 kf1 = *(const short8*)&Kbuf[t*16 + r16][32 + g*8];
      f32x4 z = {0.f, 0.f, 0.f, 0.f};
      z = MFMA16(qf0, kf0, z);
      z = MFMA16(qf1, kf1, z);
      st[t] = z;
    }

#pragma unroll
    for (int t = 0; t < 4; ++t) {
#pragma unroll
      for (int r = 0; r < 4; ++r) {
        float p = exp2f(st[t][r] - mrow[r]) * rinv[r];
        aRow[(size_t)r * 2048u + (size_t)(ch*64 + t*16 + r16)] = p;
        Pbuf[w][4*g + r][t*16 + r16] = f2bf(p);
      }
    }

#pragma unroll
    for (int c = 0; c < 2; ++c) {
      const short8 pa = *(const short8*)&Pbuf[w][r16][c*32 + g*8];
#pragma unroll
      for (int t = 0; t < 4; ++t) {
        const unsigned short* vp = &VT[t*16 + r16][c*32 + g*8];
        short4v lo = *(const short4v*)vp;
        short4v hi = *(const short4v*)(vp + 4);
        short8 vbf = { lo[0], lo[1], lo[2], lo[3], hi[0], hi[1], hi[2], hi[3] };
        oacc[t] = MFMA16(pa, vbf, oacc[t]);
      }
    }
  }

  float* op = Og + (((size_t)b * 2048u + (size_t)(q0 + w*16 + 4*g)) * 16u + (size_t)h) * 64u;
#pragma unroll
  for (int t = 0; t < 4; ++t)
#pragma unroll
    for (int r = 0; r < 4; ++r)
      op[(size_t)r * 1024u + (size_t)(t*16 + r16)] = oacc[t][r];
}

// ============================ launcher ============================

extern "C" void kernel_launch(void* const* d_in, const int* in_sizes, int n_in,
                              void* d_out, int out_size, void* d_ws, size_t ws_size,
                              hipStream_t stream) {
  const float* Q = (const float*)d_in[0];
  const float* K = (const float*)d_in[1];
  const float* V = (const float*)d_in[2];
  float* Og = (float*)d_out;               // v: 4*2048*16*64 = 8388608
  float* Ag = (float*)d_out + 8388608;     // attn_map: 4*16*2048*2048

  const size_t NEED = 2ull * 8388608ull * 2ull;  // Kbf + VTbf = 33554432 B
  if (ws_size >= NEED) {
    unsigned short* Kbf  = (unsigned short*)d_ws;
    unsigned short* VTbf = Kbf + 8388608;
    conv_all<<<dim3(6144), dim3(256), 0, stream>>>(K, V, Kbf, VTbf);
    attn_main<<<dim3(1024), dim3(512), 0, stream>>>(Q, Kbf, VTbf, Og, Ag);
  } else {
    attn_fused<<<dim3(2048), dim3(256), 0, stream>>>(Q, K, V, Og, Ag);
  }
}